// Round 1
// baseline (722.761 us; speedup 1.0000x reference)
//
#include <hip/hip_runtime.h>
#include <math.h>

#define BSZ 256
#define DIM 1024
#define VOC 50257
#define NL 2
#define NB 8
#define DH 128

typedef __bf16 bf16x8 __attribute__((ext_vector_type(8)));
typedef float  f32x4  __attribute__((ext_vector_type(4)));
typedef unsigned short u16;
typedef u16 u16x8 __attribute__((ext_vector_type(8)));

__device__ __forceinline__ u16 f2bf(float f) {
  unsigned int u = __float_as_uint(f);
  u += 0x7fffu + ((u >> 16) & 1u);   // RNE
  return (u16)(u >> 16);
}
__device__ __forceinline__ float sigm(float x) { return 1.0f / (1.0f + __expf(-x)); }

// ---------------------------------------------------------------------------
// Generic tile GEMM: C[0:256][n0:n0+64] += A(256xK bf16, row-major lda) *
// B(N x K fp32, row-major ldb)^T, bf16 MFMA 16x16x32, BK=64.
// lA[256][72], lB[64][72]: +8 pad -> 2-way max bank aliasing on ds_read_b128.
// ---------------------------------------------------------------------------
__device__ __forceinline__ void gemm_block(
    const u16* __restrict__ A, int lda,
    const float* __restrict__ B, int ldb, int n0, int nValid, int K,
    f32x4 (&acc)[4][4], u16 (*lA)[72], u16 (*lB)[72])
{
  const int tid  = threadIdx.x;
  const int wave = tid >> 6;
  const int lane = tid & 63;
  const int quad = lane >> 4;
  const int l16  = lane & 15;

  const int arow = tid >> 3;          // 0..31
  const int acol = (tid & 7) * 8;     // 0..56
  const int brow = tid >> 4;          // 0..15
  const int bcol = (tid & 15) * 4;    // 0..60

  for (int kb = 0; kb < K; kb += 64) {
    // stage A tile (256 x 64 bf16), 16B loads/stores
    const u16* Ag = A + kb + acol;
#pragma unroll
    for (int p = 0; p < 8; ++p) {
      int row = p * 32 + arow;
      u16x8 v = *(const u16x8*)(Ag + (long)row * lda);
      *(u16x8*)(&lA[row][acol]) = v;
    }
    // stage B tile (64 x 64), fp32 -> bf16 on the fly
#pragma unroll
    for (int p = 0; p < 4; ++p) {
      int row = p * 16 + brow;
      float4 v = make_float4(0.f, 0.f, 0.f, 0.f);
      if (n0 + row < nValid)
        v = *(const float4*)(B + (long)(n0 + row) * ldb + kb + bcol);
      ushort4 h;
      h.x = f2bf(v.x); h.y = f2bf(v.y); h.z = f2bf(v.z); h.w = f2bf(v.w);
      *(ushort4*)(&lB[row][bcol]) = h;
    }
    __syncthreads();
#pragma unroll
    for (int kk = 0; kk < 64; kk += 32) {
      bf16x8 aF[4], bF[4];
#pragma unroll
      for (int mi = 0; mi < 4; ++mi)
        aF[mi] = *(const bf16x8*)(&lA[wave * 64 + mi * 16 + l16][kk + quad * 8]);
#pragma unroll
      for (int ni = 0; ni < 4; ++ni)
        bF[ni] = *(const bf16x8*)(&lB[ni * 16 + l16][kk + quad * 8]);
#pragma unroll
      for (int mi = 0; mi < 4; ++mi)
#pragma unroll
        for (int ni = 0; ni < 4; ++ni)
          acc[mi][ni] = __builtin_amdgcn_mfma_f32_16x16x32_bf16(aF[mi], bF[ni], acc[mi][ni], 0, 0, 0);
    }
    __syncthreads();
  }
}

#define GEMM_PROLOG                                   \
  __shared__ u16 lA[256][72];                         \
  __shared__ u16 lB[64][72];                          \
  f32x4 acc[4][4];                                    \
  { f32x4 z = {0.f, 0.f, 0.f, 0.f};                   \
    for (int i = 0; i < 4; ++i)                       \
      for (int j = 0; j < 4; ++j) acc[i][j] = z; }

#define EPILOG_IDX                                    \
  const int tid = threadIdx.x;                        \
  const int wave = tid >> 6;                          \
  const int lane = tid & 63;                          \
  const int quad = lane >> 4;                         \
  const int l16 = lane & 15;

// ---------------------------------------------------------------------------
// K1: carry (with bool-layout detection), x gather (fp32 out + bf16), h->bf16
// ---------------------------------------------------------------------------
__global__ void k_prep(const int* __restrict__ ids, const void* __restrict__ mask,
                       const float* __restrict__ emb, const float* __restrict__ hstate,
                       float* __restrict__ xout, u16* __restrict__ x_bf,
                       u16* __restrict__ h_bf, float* __restrict__ carry)
{
  __shared__ int sInt;
  const int tid = threadIdx.x, s = blockIdx.x;
  if (tid == 0) sInt = 1;
  __syncthreads();
  if (tid < 64) {
    int v = ((const int*)mask)[tid];
    if (v != 0 && v != 1) atomicAnd(&sInt, 0);
  }
  __syncthreads();
  if (tid == 0) {
    int m = sInt ? ((const int*)mask)[s] : (int)((const unsigned char*)mask)[s];
    carry[s] = m ? 0.0f : 1.0f;
  }
  long id = ids[s];
  int k = tid * 4;
  float4 v = *(const float4*)(emb + id * DIM + k);
  *(float4*)(xout + (long)s * DIM + k) = v;
  ushort4 h; h.x = f2bf(v.x); h.y = f2bf(v.y); h.z = f2bf(v.z); h.w = f2bf(v.w);
  *(ushort4*)(x_bf + (long)s * DIM + k) = h;
#pragma unroll
  for (int l = 0; l < NL; ++l) {
    long off = (long)l * BSZ * DIM + (long)s * DIM + k;
    float4 w = *(const float4*)(hstate + off);
    ushort4 o; o.x = f2bf(w.x); o.y = f2bf(w.y); o.z = f2bf(w.z); o.w = f2bf(w.w);
    *(ushort4*)(h_bf + off) = o;
  }
}

// ---------------------------------------------------------------------------
// K2: [alpha_pre | x_proj] = x @ [W_alpha ; W_in]^T, fused wm_new epilogue
// ---------------------------------------------------------------------------
__global__ void k_gemm1(const u16* __restrict__ x_bf,
                        const float* __restrict__ W_alpha, const float* __restrict__ W_in,
                        const float* __restrict__ carry, const float* __restrict__ wm_state,
                        const float* __restrict__ xout,
                        u16* __restrict__ wm_bf, u16* __restrict__ cur_bf)
{
  GEMM_PROLOG
  int n0g = blockIdx.x * 64;
  bool isAlpha = (n0g < DIM);
  const float* Bp = isAlpha ? W_alpha : W_in;
  int n0 = isAlpha ? n0g : n0g - DIM;
  gemm_block(x_bf, DIM, Bp, DIM, n0, DIM, DIM, acc, lA, lB);
  EPILOG_IDX
#pragma unroll
  for (int mi = 0; mi < 4; ++mi)
#pragma unroll
    for (int ni = 0; ni < 4; ++ni) {
      int n = n0 + ni * 16 + l16;
#pragma unroll
      for (int r = 0; r < 4; ++r) {
        int s = wave * 64 + mi * 16 + quad * 4 + r;
        float c = acc[mi][ni][r];
        long idx = (long)s * DIM + n;
        if (isAlpha) {
          float wm = carry[s] * sigm(c) * wm_state[idx] + xout[idx];
          wm_bf[idx] = f2bf(wm);
        } else {
          cur_bf[idx] = f2bf(c);
        }
      }
    }
}

// ---------------------------------------------------------------------------
// K3: y_wm = tanh(wm_new @ W_wm_out^T)
// ---------------------------------------------------------------------------
__global__ void k_gemm2(const u16* __restrict__ wm_bf, const float* __restrict__ W_wm_out,
                        float* __restrict__ yout, u16* __restrict__ ywm_bf)
{
  GEMM_PROLOG
  int n0 = blockIdx.x * 64;
  gemm_block(wm_bf, DIM, W_wm_out, DIM, n0, DIM, DIM, acc, lA, lB);
  EPILOG_IDX
#pragma unroll
  for (int mi = 0; mi < 4; ++mi)
#pragma unroll
    for (int ni = 0; ni < 4; ++ni) {
      int n = n0 + ni * 16 + l16;
#pragma unroll
      for (int r = 0; r < 4; ++r) {
        int s = wave * 64 + mi * 16 + quad * 4 + r;
        float y = tanhf(acc[mi][ni][r]);
        long idx = (long)s * DIM + n;
        yout[idx] = y;
        ywm_bf[idx] = f2bf(y);
      }
    }
}

// ---------------------------------------------------------------------------
// K4/K6: a = cur@W_x^T + h@W_h^T + y_wm@W_wml^T   (per batch b, 3 K-phases)
// ---------------------------------------------------------------------------
__global__ void k_gemm_a(int l, const u16* __restrict__ cur_bf, const u16* __restrict__ h_bf,
                         const u16* __restrict__ ywm_bf,
                         const float* __restrict__ W_x, const float* __restrict__ W_h,
                         const float* __restrict__ W_wml,
                         float* __restrict__ a_f32, u16* __restrict__ a_bf)
{
  GEMM_PROLOG
  int b = blockIdx.x >> 1;
  int n0 = (blockIdx.x & 1) * 64;
  gemm_block(cur_bf + b * DH, DIM, W_x + (long)(l * NB + b) * DH * DH, DH, n0, DH, DH, acc, lA, lB);
  gemm_block(h_bf + (long)l * BSZ * DIM + b * DH, DIM, W_h + (long)(l * NB + b) * DH * DH, DH, n0, DH, DH, acc, lA, lB);
  gemm_block(ywm_bf, DIM, W_wml + (long)(l * NB + b) * DH * DIM, DIM, n0, DH, DIM, acc, lA, lB);
  EPILOG_IDX
#pragma unroll
  for (int mi = 0; mi < 4; ++mi)
#pragma unroll
    for (int ni = 0; ni < 4; ++ni) {
      int e = n0 + ni * 16 + l16;
#pragma unroll
      for (int r = 0; r < 4; ++r) {
        int s = wave * 64 + mi * 16 + quad * 4 + r;
        float c = acc[mi][ni][r];
        long idx = (long)s * DIM + b * DH + e;
        a_f32[idx] = c;
        a_bf[idx] = f2bf(c);
      }
    }
}

// ---------------------------------------------------------------------------
// K5/K7: g = sigmoid(a@W_g^T + surprise*w_s + b_g); h_new gating
// ---------------------------------------------------------------------------
__global__ void k_gemm_g(int l, const u16* __restrict__ a_bf, const float* __restrict__ W_g,
                         const float* __restrict__ w_s, const float* __restrict__ b_g,
                         const float* __restrict__ surprise, const float* __restrict__ carry,
                         const float* __restrict__ hstate, const float* __restrict__ a_f32,
                         u16* __restrict__ hout_bf)
{
  GEMM_PROLOG
  int b = blockIdx.x >> 1;
  int n0 = (blockIdx.x & 1) * 64;
  gemm_block(a_bf + b * DH, DIM, W_g + (long)(l * NB + b) * DH * DH, DH, n0, DH, DH, acc, lA, lB);
  EPILOG_IDX
#pragma unroll
  for (int mi = 0; mi < 4; ++mi)
#pragma unroll
    for (int ni = 0; ni < 4; ++ni) {
      int e = n0 + ni * 16 + l16;
#pragma unroll
      for (int r = 0; r < 4; ++r) {
        int s = wave * 64 + mi * 16 + quad * 4 + r;
        float c = acc[mi][ni][r];
        long idx = (long)s * DIM + b * DH + e;
        float gp = c + surprise[s] * w_s[(l * NB + b) * DH + e] + b_g[(l * NB + b) * DH + e];
        float g = sigm(gp);
        float ho = hstate[(long)l * BSZ * DIM + idx];
        float hn = carry[s] * ((1.0f - g) * ho + g * tanhf(a_f32[idx]));
        hout_bf[idx] = f2bf(hn);
      }
    }
}

// ---------------------------------------------------------------------------
// K8: logits = h_final @ emb^T   (the big one: 206 MB emb streamed, HBM-bound)
// ---------------------------------------------------------------------------
__global__ void k_logits(const u16* __restrict__ hfin_bf, const float* __restrict__ emb,
                         float* __restrict__ out)
{
  GEMM_PROLOG
  int n0 = blockIdx.x * 64;
  gemm_block(hfin_bf, DIM, emb, DIM, n0, VOC, DIM, acc, lA, lB);
  EPILOG_IDX
#pragma unroll
  for (int mi = 0; mi < 4; ++mi)
#pragma unroll
    for (int ni = 0; ni < 4; ++ni) {
      int n = n0 + ni * 16 + l16;
      if (n < VOC) {
#pragma unroll
        for (int r = 0; r < 4; ++r) {
          int s = wave * 64 + mi * 16 + quad * 4 + r;
          out[(long)s * VOC + n] = acc[mi][ni][r];
        }
      }
    }
}

extern "C" void kernel_launch(void* const* d_in, const int* in_sizes, int n_in,
                              void* d_out, int out_size, void* d_ws, size_t ws_size,
                              hipStream_t stream) {
  const int*   input_id = (const int*)d_in[0];
  const void*  reset    = d_in[1];
  const float* surprise = (const float*)d_in[2];
  const float* wm_state = (const float*)d_in[3];
  const float* h_state  = (const float*)d_in[4];
  const float* emb      = (const float*)d_in[5];
  const float* W_in     = (const float*)d_in[6];
  const float* W_alpha  = (const float*)d_in[7];
  const float* W_wm_out = (const float*)d_in[8];
  const float* W_x      = (const float*)d_in[9];
  const float* W_h      = (const float*)d_in[10];
  const float* W_wml    = (const float*)d_in[11];
  const float* W_g      = (const float*)d_in[12];
  const float* w_s      = (const float*)d_in[13];
  const float* b_g      = (const float*)d_in[14];

  float* out  = (float*)d_out;
  float* xout = out + (size_t)BSZ * VOC;          // x output (fp32, exact)
  float* yout = xout + (size_t)BSZ * DIM;         // y_wm output

  // Scratch lives in the (huge) logits region of d_out — it is only read by
  // kernels that run before k_logits, and k_logits reads nothing from d_out.
  const long SD = (long)BSZ * DIM;                // 262144
  u16* scr    = (u16*)d_out;
  u16* x_bf   = scr;                              // 256x1024
  u16* wm_bf  = scr + SD;
  u16* cur_bf = scr + 2 * SD;
  u16* ywm_bf = scr + 3 * SD;
  u16* h_bf   = scr + 4 * SD;                     // 2x256x1024
  u16* a_bf   = scr + 6 * SD;
  float* a_f32 = (float*)(scr + 8 * SD);          // 256x1024 fp32 (4MB offset)

  // h_final + carry must live OUTSIDE d_out (read while k_logits writes d_out)
  float* carry  = (float*)d_ws;
  u16* hfin_bf  = (u16*)((char*)d_ws + 1024);

  k_prep<<<BSZ, 256, 0, stream>>>(input_id, reset, emb, h_state, xout, x_bf, h_bf, carry);
  k_gemm1<<<32, 256, 0, stream>>>(x_bf, W_alpha, W_in, carry, wm_state, xout, wm_bf, cur_bf);
  k_gemm2<<<16, 256, 0, stream>>>(wm_bf, W_wm_out, yout, ywm_bf);
  k_gemm_a<<<16, 256, 0, stream>>>(0, cur_bf, h_bf, ywm_bf, W_x, W_h, W_wml, a_f32, a_bf);
  k_gemm_g<<<16, 256, 0, stream>>>(0, a_bf, W_g, w_s, b_g, surprise, carry, h_state, a_f32, cur_bf);
  k_gemm_a<<<16, 256, 0, stream>>>(1, cur_bf, h_bf, ywm_bf, W_x, W_h, W_wml, a_f32, a_bf);
  k_gemm_g<<<16, 256, 0, stream>>>(1, a_bf, W_g, w_s, b_g, surprise, carry, h_state, a_f32, hfin_bf);
  k_logits<<<(VOC + 63) / 64, 256, 0, stream>>>(hfin_bf, emb, out);
}